// Round 3
// baseline (567.745 us; speedup 1.0000x reference)
//
#include <hip/hip_runtime.h>
#include <math.h>

#define D 128
#define NF 10
#define N_IP 20000
#define N_CONN 100000
#define NE 200000
#define T_ROUNDS 3

typedef unsigned short u16;
using bf16x8 = __attribute__((ext_vector_type(8))) short;
using floatx4 = __attribute__((ext_vector_type(4))) float;

__device__ inline u16 f2bf(float f) {
  union { float f; unsigned u; } v; v.f = f;
  unsigned u = v.u;
  return (u16)((u + 0x7fffu + ((u >> 16) & 1u)) >> 16);  // RNE
}
__device__ inline float bf2f(u16 h) {
  union { unsigned u; float f; } v; v.u = ((unsigned)h) << 16; return v.f;
}

__device__ inline float fsigmoid(float s) { return 1.f / (1.f + __expf(-s)); }
__device__ inline float ftanh(float a) {
  a = fminf(fmaxf(a, -15.f), 15.f);
  float e = __expf(2.f * a);
  return (e - 1.f) / (e + 1.f);
}

// async global->LDS, 16B per lane. LDS dest is wave-linear (base + lane*16B);
// swizzled layouts are realized by pre-swizzling the per-lane GLOBAL address.
__device__ __forceinline__ void gld16(const u16* g, u16* l) {
  __builtin_amdgcn_global_load_lds(
      (const __attribute__((address_space(1))) unsigned int*)g,
      (__attribute__((address_space(3))) unsigned int*)l, 16, 0, 0);
}

// ---------------- fused init: states + cnt zero ----------------
__global__ void k_init_all(u16* __restrict__ ip_state, u16* __restrict__ conn_state,
                           const float* __restrict__ feat, int* __restrict__ cnt) {
  int i = blockIdx.x * blockDim.x + threadIdx.x;
  const int nip = N_IP * D;
  const int nstate = (N_IP + N_CONN) * D;
  if (i < nip) {
    ip_state[i] = 0x3F80;  // bf16(1.0)
  } else if (i < nstate) {
    int j = i - nip;
    int r = j >> 7, c = j & 127;
    conn_state[j] = (c < NF) ? f2bf(feat[r * NF + c]) : (u16)0;
  }
  if (i < N_CONN + N_IP) cnt[i] = 0;
}

// ---------------- fused weight prep (all matrices, bf16 [col][k]) + colsum ----------------
__global__ void k_prep_all(
    const float* __restrict__ gik, const float* __restrict__ gir,
    const float* __restrict__ gck, const float* __restrict__ gcr,
    const float* __restrict__ Wm1, const float* __restrict__ Wm2,
    const float* __restrict__ Wr1, const float* __restrict__ Wr2,
    u16* __restrict__ gikb, u16* __restrict__ girb,
    u16* __restrict__ gckb, u16* __restrict__ gcrb,
    u16* __restrict__ wm1b, u16* __restrict__ wm2b,
    u16* __restrict__ wm1t, u16* __restrict__ wm2t,
    u16* __restrict__ wr1b, u16* __restrict__ wr2b, float* __restrict__ csum) {
  int i = blockIdx.x * blockDim.x + threadIdx.x;
  if (i < 196608) {  // 4 GRU mats (128x384 -> [col][k] 384x128)
    int m = i / 49152, r = i % 49152;
    const float* W = (m == 0) ? gik : (m == 1) ? gir : (m == 2) ? gck : gcr;
    u16* Wb = (m == 0) ? gikb : (m == 1) ? girb : (m == 2) ? gckb : gcrb;
    int col = r >> 7, k = r & 127;
    Wb[r] = f2bf(W[k * 384 + col]);
  } else if (i < 278528) {  // 5 x 128x128 blocks
    int j = i - 196608;
    int m = j / 16384, r = j % 16384;
    const float* W; u16* Wb; int k0;
    if (m == 0) { W = Wm1; Wb = wm1b; k0 = 128; }
    else if (m == 1) { W = Wm2; Wb = wm2b; k0 = 128; }
    else if (m == 2) { W = Wm1; Wb = wm1t; k0 = 0; }
    else if (m == 3) { W = Wm2; Wb = wm2t; k0 = 0; }
    else { W = Wr1; Wb = wr1b; k0 = 0; }
    int col = r >> 7, k = r & 127;
    Wb[r] = f2bf(W[(k0 + k) * 128 + col]);
  } else if (i < 286720) {  // Wr2 128x64 -> [col][k] 64x128
    int r = i - 278528;
    int col = r >> 7, k = r & 127;
    wr2b[r] = f2bf(Wr2[k * 64 + col]);
  } else if (i < 286848) {  // colsum of Wm1_top (ip_state0 == 1)
    int c = i - 286720;
    float s = 0.f;
    for (int k = 0; k < 128; k++) s += Wm1[k * 128 + c];
    csum[c] = s;
  }
}

// ---------------- analytic round-0 P + degree count (merged) ----------------
__global__ void k_initP_count(const float* __restrict__ csum, const float* __restrict__ feat,
                              const float* __restrict__ Wm2,
                              u16* __restrict__ P1, u16* __restrict__ P2,
                              const int* __restrict__ d1, const int* __restrict__ d2,
                              int* __restrict__ c1, int* __restrict__ c2) {
  int i = blockIdx.x * blockDim.x + threadIdx.x;
  if (i < NE) {
    atomicAdd(&c1[d1[i]], 1);
    atomicAdd(&c2[d2[i]], 1);
  }
  const int n1 = N_IP * 16;
  const int n2 = N_CONN * 16;
  if (i < n1) {
    int r = i >> 4, g = i & 15;
    u16 v[8];
#pragma unroll
    for (int k = 0; k < 8; k++) v[k] = f2bf(csum[g * 8 + k]);
    *(uint4*)(P1 + (size_t)r * 128 + g * 8) = *(const uint4*)v;
  } else if (i < n1 + n2) {
    int j = i - n1;
    int r = j >> 4, g = j & 15;
    float acc[8] = {0.f, 0.f, 0.f, 0.f, 0.f, 0.f, 0.f, 0.f};
#pragma unroll
    for (int k = 0; k < NF; k++) {
      float f = feat[(size_t)r * NF + k];
      const float* wrow = Wm2 + (size_t)k * 128 + g * 8;
#pragma unroll
      for (int c = 0; c < 8; c++) acc[c] += f * wrow[c];
    }
    u16 v[8];
#pragma unroll
    for (int c = 0; c < 8; c++) v[c] = f2bf(acc[c]);
    *(uint4*)(P2 + (size_t)r * 128 + g * 8) = *(const uint4*)v;
  }
}

// ---------------- merged 3-pass exclusive scan (both segment arrays) ----------------
__global__ void k_scan_part2(const int* __restrict__ cnt1, int* __restrict__ bsum1,
                             int n1, int nb1,
                             const int* __restrict__ cnt2, int* __restrict__ bsum2, int n2) {
  const int* cnt; int* bsum; int n, b;
  if ((int)blockIdx.x < nb1) { cnt = cnt1; bsum = bsum1; n = n1; b = blockIdx.x; }
  else { cnt = cnt2; bsum = bsum2; n = n2; b = blockIdx.x - nb1; }
  int t = threadIdx.x;
  int base = b * 1024 + t * 4;
  int s = 0;
#pragma unroll
  for (int i = 0; i < 4; i++) { int j = base + i; if (j < n) s += cnt[j]; }
  for (int d = 32; d > 0; d >>= 1) s += __shfl_xor(s, d, 64);
  __shared__ int wred[4];
  int lane = t & 63, wv = t >> 6;
  if (lane == 0) wred[wv] = s;
  __syncthreads();
  if (t == 0) bsum[b] = wred[0] + wred[1] + wred[2] + wred[3];
}

__device__ inline void scan_mid_body(int* bsum, int m, int t) {
  int v = (t < m) ? bsum[t] : 0;
  int lane = t & 63, wv = t >> 6;
  int x = v;
  for (int d = 1; d < 64; d <<= 1) { int y = __shfl_up(x, d, 64); if (lane >= d) x += y; }
  __shared__ int wsum[4];
  if (lane == 63) wsum[wv] = x;
  __syncthreads();
  int add = 0;
  for (int i = 0; i < wv; i++) add += wsum[i];
  int ex = add + x - v;
  if (t < m) bsum[t] = ex;
  __syncthreads();
}

__global__ void k_scan_mid2(int* __restrict__ bsum1, int m1, int* __restrict__ bsum2, int m2) {
  int t = threadIdx.x;
  scan_mid_body(bsum1, m1, t);
  scan_mid_body(bsum2, m2, t);
}

// pass 3: write off AND cur
__global__ void k_scan_final2(const int* __restrict__ cnt1, const int* __restrict__ bsum1,
                              int* __restrict__ off1, int* __restrict__ cur1, int n1, int nb1,
                              const int* __restrict__ cnt2, const int* __restrict__ bsum2,
                              int* __restrict__ off2, int* __restrict__ cur2, int n2) {
  const int* cnt; const int* bsum; int* off; int* cur; int n, b;
  if ((int)blockIdx.x < nb1) {
    cnt = cnt1; bsum = bsum1; off = off1; cur = cur1; n = n1; b = blockIdx.x;
  } else {
    cnt = cnt2; bsum = bsum2; off = off2; cur = cur2; n = n2; b = blockIdx.x - nb1;
  }
  int t = threadIdx.x;
  int base = b * 1024 + t * 4;
  int vals[4]; int s = 0;
#pragma unroll
  for (int i = 0; i < 4; i++) {
    int j = base + i;
    vals[i] = (j < n) ? cnt[j] : 0;
    s += vals[i];
  }
  int lane = t & 63, wv = t >> 6;
  int x = s;
  for (int d = 1; d < 64; d <<= 1) { int y = __shfl_up(x, d, 64); if (lane >= d) x += y; }
  __shared__ int wsum[4];
  if (lane == 63) wsum[wv] = x;
  __syncthreads();
  int add = 0;
  for (int i = 0; i < wv; i++) add += wsum[i];
  int run = add + x - s + bsum[b];
#pragma unroll
  for (int i = 0; i < 4; i++) {
    int j = base + i;
    if (j < n) { off[j] = run; cur[j] = run; }
    run += vals[i];
  }
}

__global__ void k_scatter(const int* __restrict__ s1, const int* __restrict__ d1,
                          const int* __restrict__ s2, const int* __restrict__ d2,
                          int* __restrict__ cur1, int* __restrict__ cur2,
                          int* __restrict__ o1, int* __restrict__ o2) {
  int e = blockIdx.x * blockDim.x + threadIdx.x;
  if (e >= NE) return;
  int p1 = atomicAdd(&cur1[d1[e]], 1);
  o1[p1] = s1[e];
  int p2 = atomicAdd(&cur2[d2[e]], 1);
  o2[p2] = s2[e];
}

// ---------------- fused message+GRU+nextP (40960 B LDS, 4 blocks/CU, no spill) ----------------
// All LDS staging via global_load_lds (zero staging VGPRs); GEMM B-fragments for the
// Q-GEMM / P-GEMM read directly from global (all 4 waves read the same 32KB -> L1-hot).
// GRU weights ping-pong staged as x/h 12KB halves so loads overlap MFMAs.
// LDS map: Qb/Xb overlay [0,16384) | bufA [0,12288) bufB [12288,24576) (GRU phase)
//          offLs/cntLs [24064,24576) (dead before GRU) | Hls [24576,40960)
__global__ __launch_bounds__(256, 4) void k_msggru(
    u16* __restrict__ st1, const u16* __restrict__ wq1, const float* __restrict__ qb1,
    const u16* __restrict__ P1g, const int* __restrict__ srcs1g,
    const int* __restrict__ off1g, const int* __restrict__ cnt1g,
    const u16* __restrict__ wx1, const u16* __restrict__ wh1, const float* __restrict__ gb1,
    const u16* __restrict__ wp1, u16* __restrict__ Pn1, int r1, int tiles1,
    u16* __restrict__ st2, const u16* __restrict__ wq2, const float* __restrict__ qb2,
    const u16* __restrict__ P2g, const int* __restrict__ srcs2g,
    const int* __restrict__ off2g, const int* __restrict__ cnt2g,
    const u16* __restrict__ wx2, const u16* __restrict__ wh2, const float* __restrict__ gb2,
    const u16* __restrict__ wp2, u16* __restrict__ Pn2, int r2, int doP) {
  __shared__ __align__(16) char smem[40960];
  u16* Qb = (u16*)smem;                    // 64x128 bf16 (16KB); Xb overlays swizzled
  u16* bufA = (u16*)smem;                  // GRU x-gates chunk (12KB)
  u16* bufB = (u16*)(smem + 12288);        // GRU h-gates chunk (12KB)
  u16* Hls = (u16*)(smem + 24576);         // 64x128 bf16 swizzled (16KB), whole kernel
  int* offLs = (int*)(smem + 24064);       // 256B, dead before GRU
  int* cntLs = (int*)(smem + 24320);       // 256B
  u16* H; const u16* Wqb; const float* qbias; const u16* P;
  const int* srcs; const int* off; const int* cnt;
  const u16* Wxb; const u16* Whb; const float* gbias;
  const u16* Wpt; u16* Pn; int rows, bm;
  if ((int)blockIdx.x < tiles1) {
    H = st1; Wqb = wq1; qbias = qb1; P = P1g; srcs = srcs1g; off = off1g; cnt = cnt1g;
    Wxb = wx1; Whb = wh1; gbias = gb1; Wpt = wp1; Pn = Pn1; rows = r1; bm = blockIdx.x * 64;
  } else {
    H = st2; Wqb = wq2; qbias = qb2; P = P2g; srcs = srcs2g; off = off2g; cnt = cnt2g;
    Wxb = wx2; Whb = wh2; gbias = gb2; Wpt = wp2; Pn = Pn2; rows = r2;
    bm = (blockIdx.x - tiles1) * 64;
  }
  const int tid = threadIdx.x, wv = tid >> 6, lane = tid & 63;
  const int lrow = lane & 15, quad = lane >> 4;
  const int c4 = lane >> 4, slot = lane & 15;
  const int rowl = wv * 4 + c4;  // 0..15, local row/col of this lane's 16B chunk
  // --- phase A: H -> Hls via global_load_lds (linear LDS, pre-swizzled source) ---
  // Hls[row*128 + s*8] = H[(bm+row)*128 + (s^(row&15))*8]; OOB rows read in-workspace
  // garbage; those rows never feed a valid output (all writeouts mask grow<rows).
#pragma unroll
  for (int i = 0; i < 4; i++) {
    gld16(H + (size_t)(bm + i * 16 + rowl) * 128 + ((slot ^ rowl) * 8),
          Hls + (size_t)(i * 16 + wv * 4) * 128 + lane * 8);
  }
  if (tid < 64) {
    int node = bm + tid;
    offLs[tid] = (node < rows) ? off[node] : 0;
    cntLs[tid] = (node < rows) ? cnt[node] : 0;
  }
  __syncthreads();
  // state A-frags (serve Q-GEMM and GRU h-GEMM)
  bf16x8 ah[4];
#pragma unroll
  for (int ks = 0; ks < 4; ks++)
    ah[ks] = *(const bf16x8*)(Hls + (size_t)(wv * 16 + lrow) * 128 + (((ks * 4 + quad) ^ lrow) * 8));
  // --- Q-GEMM: B-fragments straight from global (L1-hot across the 4 waves) ---
  floatx4 acc[8];
#pragma unroll
  for (int ct = 0; ct < 8; ct++) acc[ct] = {0.f, 0.f, 0.f, 0.f};
#pragma unroll
  for (int ks = 0; ks < 4; ks++) {
#pragma unroll
    for (int ct = 0; ct < 8; ct++) {
      bf16x8 b = *(const bf16x8*)(Wqb + (size_t)(ct * 16 + lrow) * 128 + (4 * ks + quad) * 8);
      acc[ct] = __builtin_amdgcn_mfma_f32_16x16x32_bf16(ah[ks], b, acc[ct], 0, 0, 0);
    }
  }
  // --- write Q (+bias) as bf16, plain [row][col]; no prior user of region0 -> no barrier
#pragma unroll
  for (int ct = 0; ct < 8; ct++) {
    int col = ct * 16 + lrow;
    float bv = qbias[col];
#pragma unroll
    for (int reg = 0; reg < 4; reg++) {
      int lr = wv * 16 + quad * 4 + reg;
      Qb[(size_t)lr * 128 + col] = f2bf(acc[ct][reg] + bv);
    }
  }
  __syncthreads();
  // --- gather-mean: X[node] = mean_e relu(P[src_e] + Q[node]) -> Xb (=Qb, swizzled slots)
#pragma unroll
  for (int it = 0; it < 4; it++) {
    int task = it * 256 + tid;
    int nl = task >> 4, g = task & 15;
    int node = bm + nl;
    if (node >= rows) continue;
    int c8 = g << 3;
    float q[8];
    {
      uint4 qv = *(const uint4*)(Qb + (size_t)nl * 128 + c8);
      unsigned qq[4] = {qv.x, qv.y, qv.z, qv.w};
#pragma unroll
      for (int k = 0; k < 4; k++) {
        q[2 * k] = __uint_as_float(qq[k] << 16);
        q[2 * k + 1] = __uint_as_float(qq[k] & 0xffff0000u);
      }
    }
    float acg[8] = {0.f, 0.f, 0.f, 0.f, 0.f, 0.f, 0.f, 0.f};
    int o = offLs[nl], n = cntLs[nl];
    int i = 0;
    for (; i + 4 <= n; i += 4) {
      int s0 = srcs[o + i], s1 = srcs[o + i + 1], s2 = srcs[o + i + 2], s3 = srcs[o + i + 3];
      uint4 v0 = *(const uint4*)(P + (size_t)s0 * 128 + c8);
      uint4 v1 = *(const uint4*)(P + (size_t)s1 * 128 + c8);
      uint4 v2 = *(const uint4*)(P + (size_t)s2 * 128 + c8);
      uint4 v3 = *(const uint4*)(P + (size_t)s3 * 128 + c8);
      unsigned w[16] = {v0.x, v0.y, v0.z, v0.w, v1.x, v1.y, v1.z, v1.w,
                        v2.x, v2.y, v2.z, v2.w, v3.x, v3.y, v3.z, v3.w};
#pragma unroll
      for (int e = 0; e < 4; e++)
#pragma unroll
        for (int k = 0; k < 4; k++) {
          unsigned ww = w[e * 4 + k];
          float lo = __uint_as_float(ww << 16);
          float hi = __uint_as_float(ww & 0xffff0000u);
          acg[2 * k] += fmaxf(lo + q[2 * k], 0.f);
          acg[2 * k + 1] += fmaxf(hi + q[2 * k + 1], 0.f);
        }
    }
    for (; i < n; i++) {
      int s0 = srcs[o + i];
      uint4 v0 = *(const uint4*)(P + (size_t)s0 * 128 + c8);
      unsigned w[4] = {v0.x, v0.y, v0.z, v0.w};
#pragma unroll
      for (int k = 0; k < 4; k++) {
        unsigned ww = w[k];
        float lo = __uint_as_float(ww << 16);
        float hi = __uint_as_float(ww & 0xffff0000u);
        acg[2 * k] += fmaxf(lo + q[2 * k], 0.f);
        acg[2 * k + 1] += fmaxf(hi + q[2 * k + 1], 0.f);
      }
    }
    float inv = 1.f / fmaxf((float)n, 1.f);
    bf16x8 ov;
#pragma unroll
    for (int k = 0; k < 8; k++) ov[k] = (short)f2bf(acg[k] * inv);
    *(bf16x8*)(Qb + (size_t)nl * 128 + ((g ^ (nl & 15)) * 8)) = ov;  // Xb overlay
  }
  __syncthreads();
  // --- x A-frags from Xb (= Qb region, swizzled) ---
  bf16x8 ax[4];
#pragma unroll
  for (int ks = 0; ks < 4; ks++)
    ax[ks] = *(const bf16x8*)(Qb + (size_t)(wv * 16 + lrow) * 128 + (((ks * 4 + quad) ^ lrow) * 8));
  const int lr0 = wv * 16 + quad * 4;
  __syncthreads();  // all Xb/Qb reads done; region0 free for GRU staging
  // --- GRU chunk loop: x/h ping-pong via global_load_lds ---
  // bufX[(j*16+c)*128 + s*8] = W[(j*128 + ch*16 + c)*128 + (s^c)*8]
#pragma unroll
  for (int j = 0; j < 3; j++)  // stage x(0) -> bufA
    gld16(Wxb + (size_t)(j * 128 + 0 * 16 + rowl) * 128 + ((slot ^ rowl) * 8),
          bufA + (size_t)(j * 16 + wv * 4) * 128 + lane * 8);
  for (int ch = 0; ch < 8; ch++) {
    __syncthreads();  // bufA=x(ch) loaded; prev bufB reads done
#pragma unroll
    for (int j = 0; j < 3; j++)  // stage h(ch) -> bufB (overlaps MFMA-x)
      gld16(Whb + (size_t)(j * 128 + ch * 16 + rowl) * 128 + ((slot ^ rowl) * 8),
            bufB + (size_t)(j * 16 + wv * 4) * 128 + lane * 8);
    floatx4 gacc[3][2];
#pragma unroll
    for (int g = 0; g < 3; g++) {
      gacc[g][0] = {0.f, 0.f, 0.f, 0.f};
      gacc[g][1] = {0.f, 0.f, 0.f, 0.f};
    }
#pragma unroll
    for (int ks = 0; ks < 4; ks++) {
      int posu = ((4 * ks + quad) ^ lrow) * 8;
#pragma unroll
      for (int g = 0; g < 3; g++) {
        bf16x8 bx = *(const bf16x8*)(bufA + (size_t)(g * 16 + lrow) * 128 + posu);
        gacc[g][0] = __builtin_amdgcn_mfma_f32_16x16x32_bf16(ax[ks], bx, gacc[g][0], 0, 0, 0);
      }
    }
    __syncthreads();  // bufB=h(ch) loaded; bufA reads done
    if (ch < 7) {
#pragma unroll
      for (int j = 0; j < 3; j++)  // stage x(ch+1) -> bufA (overlaps MFMA-h + epilogue)
        gld16(Wxb + (size_t)(j * 128 + (ch + 1) * 16 + rowl) * 128 + ((slot ^ rowl) * 8),
              bufA + (size_t)(j * 16 + wv * 4) * 128 + lane * 8);
    }
#pragma unroll
    for (int ks = 0; ks < 4; ks++) {
      int posu = ((4 * ks + quad) ^ lrow) * 8;
#pragma unroll
      for (int g = 0; g < 3; g++) {
        bf16x8 bh = *(const bf16x8*)(bufB + (size_t)(g * 16 + lrow) * 128 + posu);
        gacc[g][1] = __builtin_amdgcn_mfma_f32_16x16x32_bf16(ah[ks], bh, gacc[g][1], 0, 0, 0);
      }
    }
    int hcol = ch * 16 + lrow;
    float bxz = gbias[hcol];
    float bxr = gbias[128 + hcol];
    float bxh = gbias[256 + hcol];
    float bhz = gbias[384 + hcol];
    float bhr = gbias[384 + 128 + hcol];
    float bhh = gbias[384 + 256 + hcol];
    int ggr = 2 * ch + (lrow >> 3);
    int gel = lrow & 7;
#pragma unroll
    for (int reg = 0; reg < 4; reg++) {
      int lr = lr0 + reg;
      float xz = gacc[0][0][reg] + bxz;
      float xr = gacc[1][0][reg] + bxr;
      float xh = gacc[2][0][reg] + bxh;
      float hz = gacc[0][1][reg] + bhz;
      float hr = gacc[1][1][reg] + bhr;
      float hh = gacc[2][1][reg] + bhh;
      float z = fsigmoid(xz + hz);
      float rr = fsigmoid(xr + hr);
      float hc = ftanh(xh + rr * hh);
      u16* hp = Hls + (size_t)lr * 128 + ((ggr ^ (lr & 15)) * 8) + gel;
      float hold = bf2f(*hp);
      *hp = f2bf(z * hold + (1.f - z) * hc);
    }
  }
  __syncthreads();
  // --- coalesced state write-out ---
#pragma unroll
  for (int i = 0; i < 4; i++) {
    int task = i * 256 + tid;
    int row = task >> 4, g = task & 15;
    int grow = bm + row;
    if (grow < rows)
      *(uint4*)(H + (size_t)grow * 128 + g * 8) =
          *(const uint4*)(Hls + (size_t)row * 128 + ((g ^ (row & 15)) * 8));
  }
  if (!doP) return;
  // --- fused next-round P: Pn = h_new @ Wm_top, B-fragments direct from global ---
  bf16x8 ah2[4];
#pragma unroll
  for (int ks = 0; ks < 4; ks++)
    ah2[ks] = *(const bf16x8*)(Hls + (size_t)(wv * 16 + lrow) * 128 + (((ks * 4 + quad) ^ lrow) * 8));
#pragma unroll
  for (int ct = 0; ct < 8; ct++) acc[ct] = {0.f, 0.f, 0.f, 0.f};
#pragma unroll
  for (int ks = 0; ks < 4; ks++) {
#pragma unroll
    for (int ct = 0; ct < 8; ct++) {
      bf16x8 b = *(const bf16x8*)(Wpt + (size_t)(ct * 16 + lrow) * 128 + (4 * ks + quad) * 8);
      acc[ct] = __builtin_amdgcn_mfma_f32_16x16x32_bf16(ah2[ks], b, acc[ct], 0, 0, 0);
    }
  }
  __syncthreads();  // all Hls reads (writeout + ah2) drained block-wide
  u16* Cls = Hls;   // bounce over dead state tile
#pragma unroll
  for (int ct = 0; ct < 8; ct++) {
    int col = ct * 16 + lrow;
#pragma unroll
    for (int reg = 0; reg < 4; reg++) {
      int lr = wv * 16 + quad * 4 + reg;
      Cls[(size_t)lr * 128 + col] = f2bf(acc[ct][reg]);
    }
  }
  __syncthreads();
#pragma unroll
  for (int i = 0; i < 4; i++) {
    int task = i * 256 + tid;
    int row = task >> 4, g = task & 15;
    int grow = bm + row;
    if (grow < rows)
      *(uint4*)(Pn + (size_t)grow * 128 + g * 8) =
          *(const uint4*)(Cls + (size_t)row * 128 + g * 8);
  }
}

// ---------------- fully fused readout: 2 GEMMs (B direct) + parallel logits+softmax ----------------
__global__ __launch_bounds__(256, 4) void k_readout2(
    const u16* __restrict__ S, const u16* __restrict__ W1b, const float* __restrict__ b1,
    const u16* __restrict__ W2b, const float* __restrict__ b2,
    const float* __restrict__ W3, const float* __restrict__ b3,
    float* __restrict__ out, int M) {
  __shared__ __align__(16) char smem[17408];
  u16* H1ls = (u16*)smem;                       // 64 x 136 bf16
  u16* H2ls = (u16*)smem;                       // 64 x 72 bf16 (overlays H1)
  float* W3ls = (float*)(smem + 9216);          // 960 f32
  float* b3ls = (float*)(smem + 9216 + 3840);
  const int tid = threadIdx.x, wv = tid >> 6, lane = tid & 63;
  const int lrow = lane & 15, quad = lane >> 4;
  const int bm = blockIdx.x * 64;
  const int arow = bm + wv * 16 + lrow;
  const bool arv = arow < M;
  const bf16x8 zv = {0, 0, 0, 0, 0, 0, 0, 0};
  bf16x8 a[4];
#pragma unroll
  for (int ks = 0; ks < 4; ks++)
    a[ks] = arv ? *(const bf16x8*)(S + (size_t)arow * 128 + quad * 8 + ks * 32) : zv;
  floatx4 acc1[8];
#pragma unroll
  for (int ct = 0; ct < 8; ct++) acc1[ct] = {0.f, 0.f, 0.f, 0.f};
#pragma unroll
  for (int ks = 0; ks < 4; ks++) {
#pragma unroll
    for (int ct = 0; ct < 8; ct++) {
      bf16x8 b = *(const bf16x8*)(W1b + (size_t)(ct * 16 + lrow) * 128 + (4 * ks + quad) * 8);
      acc1[ct] = __builtin_amdgcn_mfma_f32_16x16x32_bf16(a[ks], b, acc1[ct], 0, 0, 0);
    }
  }
#pragma unroll
  for (int ct = 0; ct < 8; ct++) {
    int col = ct * 16 + lrow;
    float bv = b1[col];
#pragma unroll
    for (int reg = 0; reg < 4; reg++) {
      int lr = wv * 16 + quad * 4 + reg;
      H1ls[(size_t)lr * 136 + col] = f2bf(fmaxf(acc1[ct][reg] + bv, 0.f));
    }
  }
  __syncthreads();
  bf16x8 a2[4];
#pragma unroll
  for (int ks = 0; ks < 4; ks++)
    a2[ks] = *(const bf16x8*)(H1ls + (size_t)(wv * 16 + lrow) * 136 + quad * 8 + ks * 32);
  floatx4 acc2[4];
#pragma unroll
  for (int ct = 0; ct < 4; ct++) acc2[ct] = {0.f, 0.f, 0.f, 0.f};
#pragma unroll
  for (int ks = 0; ks < 4; ks++) {
#pragma unroll
    for (int ct = 0; ct < 4; ct++) {
      bf16x8 b = *(const bf16x8*)(W2b + (size_t)(ct * 16 + lrow) * 128 + (4 * ks + quad) * 8);
      acc2[ct] = __builtin_amdgcn_mfma_f32_16x16x32_bf16(a2[ks], b, acc2[ct], 0, 0, 0);
    }
  }
  __syncthreads();  // H1 reads done; region becomes H2/W3
#pragma unroll
  for (int ct = 0; ct < 4; ct++) {
    int col = ct * 16 + lrow;
    float bv = b2[col];
#pragma unroll
    for (int reg = 0; reg < 4; reg++) {
      int lr = wv * 16 + quad * 4 + reg;
      H2ls[(size_t)lr * 72 + col] = f2bf(fmaxf(acc2[ct][reg] + bv, 0.f));
    }
  }
  for (int l = tid; l < 960; l += 256) W3ls[l] = W3[l];
  if (tid < 15) b3ls[tid] = b3[tid];
  __syncthreads();
  // --- parallel logits: thread = (row-group, col); 16-lane shuffle softmax ---
  {
    int col = tid & 15;         // 0..14 valid, 15 idle
    int rb = (tid >> 4) * 4;    // 4 rows per thread
    float lg[4] = {0.f, 0.f, 0.f, 0.f};
    if (col < 15) {
      float b3v = b3ls[col];
      lg[0] = b3v; lg[1] = b3v; lg[2] = b3v; lg[3] = b3v;
      for (int k = 0; k < 64; k++) {
        float w = W3ls[k * 15 + col];
#pragma unroll
        for (int r = 0; r < 4; r++)
          lg[r] += bf2f(H2ls[(size_t)(rb + r) * 72 + k]) * w;
      }
    }
#pragma unroll
    for (int r = 0; r < 4; r++) {
      float v = (col < 15) ? lg[r] : -3.0e38f;
      float m = v;
#pragma unroll
      for (int d = 1; d < 16; d <<= 1) m = fmaxf(m, __shfl_xor(m, d, 16));
      float e = (col < 15) ? __expf(lg[r] - m) : 0.f;
      float s = e;
#pragma unroll
      for (int d = 1; d < 16; d <<= 1) s += __shfl_xor(s, d, 16);
      int gr2 = bm + rb + r;
      if (col < 15 && gr2 < M) out[(size_t)gr2 * 15 + col] = e / s;
    }
  }
}

// ---------------- launch ----------------
extern "C" void kernel_launch(void* const* d_in, const int* in_sizes, int n_in,
                              void* d_out, int out_size, void* d_ws, size_t ws_size,
                              hipStream_t stream) {
  const float* feat = (const float*)d_in[0];
  const int* src1 = (const int*)d_in[1];
  const int* dst1 = (const int*)d_in[2];
  const int* src2 = (const int*)d_in[3];
  const int* dst2 = (const int*)d_in[4];
  const float* Wm1 = (const float*)d_in[5];
  const float* bm1 = (const float*)d_in[6];
  const float* Wm2 = (const float*)d_in[7];
  const float* bm2 = (const float*)d_in[8];
  const float* gik = (const float*)d_in[9];
  const float* gir = (const float*)d_in[10];
  const float* gib = (const float*)d_in[11];
  const float* gck = (const float*)d_in[12];
  const float* gcr = (const float*)d_in[13];
  const float* gcb = (const float*)d_in[14];
  const float* Wr1 = (const float*)d_in[15];
  const float* br1 = (const float*)d_in[16];
  const float* Wr2 = (const float*)d_in[17];
  const float* br2 = (const float*)d_in[18];
  const float* Wr3 = (const float*)d_in[19];
  const float* br3 = (const float*)d_in[20];
  float* out = (float*)d_out;

  // ---- workspace layout (u16 units) ----
  u16* w16 = (u16*)d_ws;
  size_t o = 0;
  u16* ip_state = w16 + o;   o += (size_t)N_IP * D;
  u16* conn_state = w16 + o; o += (size_t)N_CONN * D;
  u16* P1a = w16 + o;        o += (size_t)N_IP * D;
  u16* P2a = w16 + o;        o += (size_t)N_CONN * D;
  u16* P1b = w16 + o;        o += (size_t)N_IP * D;
  u16* P2b = w16 + o;        o += (size_t)N_CONN * D;
  u16* gikb = w16 + o;       o += 49152;
  u16* girb = w16 + o;       o += 49152;
  u16* gckb = w16 + o;       o += 49152;
  u16* gcrb = w16 + o;       o += 49152;
  u16* wm1b = w16 + o;       o += 16384;
  u16* wm2b = w16 + o;       o += 16384;
  u16* wm1t = w16 + o;       o += 16384;
  u16* wm2t = w16 + o;       o += 16384;
  u16* wr1b = w16 + o;       o += 16384;
  u16* wr2b = w16 + o;       o += 8192;
  float* csum = (float*)(w16 + o); o += 256;
  int* ip = (int*)(w16 + o);
  int* cnt1 = ip;  ip += N_CONN;
  int* cnt2 = ip;  ip += N_IP;
  int* off1 = ip;  ip += N_CONN;
  int* off2 = ip;  ip += N_IP;
  int* cur1 = ip;  ip += N_CONN;
  int* cur2 = ip;  ip += N_IP;
  int* srcs1 = ip; ip += NE;
  int* srcs2 = ip; ip += NE;
  int* bsum1 = ip; ip += 256;
  int* bsum2 = ip; ip += 256;

  const int BT = 256;

  // ---- fused init + weight prep (+colsum) + analytic round-0 P (+count) ----
  const int nstate = (N_IP + N_CONN) * D;
  k_init_all<<<(nstate + BT - 1) / BT, BT, 0, stream>>>(ip_state, conn_state, feat, cnt1);
  k_prep_all<<<(286848 + BT - 1) / BT, BT, 0, stream>>>(
      gik, gir, gck, gcr, Wm1, Wm2, Wr1, Wr2,
      gikb, girb, gckb, gcrb, wm1b, wm2b, wm1t, wm2t, wr1b, wr2b, csum);
  const int nPinit = (N_IP + N_CONN) * 16;
  k_initP_count<<<(nPinit + BT - 1) / BT, BT, 0, stream>>>(
      csum, feat, Wm2, P1a, P2a, dst1, dst2, cnt1, cnt2);

  // ---- build CSR ----
  const int nb1 = (N_CONN + 1023) / 1024, nb2 = (N_IP + 1023) / 1024;
  k_scan_part2<<<nb1 + nb2, 256, 0, stream>>>(cnt1, bsum1, N_CONN, nb1, cnt2, bsum2, N_IP);
  k_scan_mid2<<<1, 256, 0, stream>>>(bsum1, nb1, bsum2, nb2);
  k_scan_final2<<<nb1 + nb2, 256, 0, stream>>>(cnt1, bsum1, off1, cur1, N_CONN, nb1,
                                               cnt2, bsum2, off2, cur2, N_IP);
  k_scatter<<<(NE + BT - 1) / BT, BT, 0, stream>>>(src1, dst1, src2, dst2,
                                                   cur1, cur2, srcs1, srcs2);

  const int t64ip = (N_IP + 63) / 64;       // 313
  const int t64cn = (N_CONN + 63) / 64;     // 1563

  u16* P1buf[2] = {P1a, P1b};
  u16* P2buf[2] = {P2a, P2b};
  for (int t = 0; t < T_ROUNDS; t++) {
    int cu = t & 1, nx = cu ^ 1;
    // ip side FIRST (heaviest gather blocks -> better makespan), conn side second.
    // Each side also emits next round's P from the freshly updated state (ping-pong).
    k_msggru<<<t64ip + t64cn, 256, 0, stream>>>(
        ip_state, wm2b, bm2, P2buf[cu], srcs2, off2, cnt2, gikb, girb, gib,
        wm1t, P1buf[nx], N_IP, t64ip,
        conn_state, wm1b, bm1, P1buf[cu], srcs1, off1, cnt1, gckb, gcrb, gcb,
        wm2t, P2buf[nx], N_CONN, (t < T_ROUNDS - 1) ? 1 : 0);
  }

  k_readout2<<<t64cn, 256, 0, stream>>>(conn_state, wr1b, br1, wr2b, br2,
                                        Wr3, br3, out, N_CONN);
}

// Round 4
// 447.352 us; speedup vs baseline: 1.2691x; 1.2691x over previous
//
#include <hip/hip_runtime.h>
#include <math.h>

#define D 128
#define NF 10
#define N_IP 20000
#define N_CONN 100000
#define NE 200000
#define T_ROUNDS 3

typedef unsigned short u16;
using bf16x8 = __attribute__((ext_vector_type(8))) short;
using floatx4 = __attribute__((ext_vector_type(4))) float;

__device__ inline u16 f2bf(float f) {
  union { float f; unsigned u; } v; v.f = f;
  unsigned u = v.u;
  return (u16)((u + 0x7fffu + ((u >> 16) & 1u)) >> 16);  // RNE
}
__device__ inline float bf2f(u16 h) {
  union { unsigned u; float f; } v; v.u = ((unsigned)h) << 16; return v.f;
}

__device__ inline float fsigmoid(float s) { return 1.f / (1.f + __expf(-s)); }
__device__ inline float ftanh(float a) {
  a = fminf(fmaxf(a, -15.f), 15.f);
  float e = __expf(2.f * a);
  return (e - 1.f) / (e + 1.f);
}

// async global->LDS, 16B per lane. LDS dest is wave-linear (base + lane*16B);
// swizzled layouts are realized by pre-swizzling the per-lane GLOBAL address.
__device__ __forceinline__ void gld16(const u16* g, u16* l) {
  __builtin_amdgcn_global_load_lds(
      (const __attribute__((address_space(1))) unsigned int*)g,
      (__attribute__((address_space(3))) unsigned int*)l, 16, 0, 0);
}

// ---------------- fused init: states + cnt zero ----------------
__global__ void k_init_all(u16* __restrict__ ip_state, u16* __restrict__ conn_state,
                           const float* __restrict__ feat, int* __restrict__ cnt) {
  int i = blockIdx.x * blockDim.x + threadIdx.x;
  const int nip = N_IP * D;
  const int nstate = (N_IP + N_CONN) * D;
  if (i < nip) {
    ip_state[i] = 0x3F80;  // bf16(1.0)
  } else if (i < nstate) {
    int j = i - nip;
    int r = j >> 7, c = j & 127;
    conn_state[j] = (c < NF) ? f2bf(feat[r * NF + c]) : (u16)0;
  }
  if (i < N_CONN + N_IP) cnt[i] = 0;
}

// ---------------- fused weight prep (all matrices, bf16 [col][k]) + colsum ----------------
__global__ void k_prep_all(
    const float* __restrict__ gik, const float* __restrict__ gir,
    const float* __restrict__ gck, const float* __restrict__ gcr,
    const float* __restrict__ Wm1, const float* __restrict__ Wm2,
    const float* __restrict__ Wr1, const float* __restrict__ Wr2,
    u16* __restrict__ gikb, u16* __restrict__ girb,
    u16* __restrict__ gckb, u16* __restrict__ gcrb,
    u16* __restrict__ wm1b, u16* __restrict__ wm2b,
    u16* __restrict__ wm1t, u16* __restrict__ wm2t,
    u16* __restrict__ wr1b, u16* __restrict__ wr2b, float* __restrict__ csum) {
  int i = blockIdx.x * blockDim.x + threadIdx.x;
  if (i < 196608) {  // 4 GRU mats (128x384 -> [col][k] 384x128)
    int m = i / 49152, r = i % 49152;
    const float* W = (m == 0) ? gik : (m == 1) ? gir : (m == 2) ? gck : gcr;
    u16* Wb = (m == 0) ? gikb : (m == 1) ? girb : (m == 2) ? gckb : gcrb;
    int col = r >> 7, k = r & 127;
    Wb[r] = f2bf(W[k * 384 + col]);
  } else if (i < 278528) {  // 5 x 128x128 blocks
    int j = i - 196608;
    int m = j / 16384, r = j % 16384;
    const float* W; u16* Wb; int k0;
    if (m == 0) { W = Wm1; Wb = wm1b; k0 = 128; }
    else if (m == 1) { W = Wm2; Wb = wm2b; k0 = 128; }
    else if (m == 2) { W = Wm1; Wb = wm1t; k0 = 0; }
    else if (m == 3) { W = Wm2; Wb = wm2t; k0 = 0; }
    else { W = Wr1; Wb = wr1b; k0 = 0; }
    int col = r >> 7, k = r & 127;
    Wb[r] = f2bf(W[(k0 + k) * 128 + col]);
  } else if (i < 286720) {  // Wr2 128x64 -> [col][k] 64x128
    int r = i - 278528;
    int col = r >> 7, k = r & 127;
    wr2b[r] = f2bf(Wr2[k * 64 + col]);
  } else if (i < 286848) {  // colsum of Wm1_top (ip_state0 == 1)
    int c = i - 286720;
    float s = 0.f;
    for (int k = 0; k < 128; k++) s += Wm1[k * 128 + c];
    csum[c] = s;
  }
}

// ---------------- analytic round-0 P + degree count (merged) ----------------
__global__ void k_initP_count(const float* __restrict__ csum, const float* __restrict__ feat,
                              const float* __restrict__ Wm2,
                              u16* __restrict__ P1, u16* __restrict__ P2,
                              const int* __restrict__ d1, const int* __restrict__ d2,
                              int* __restrict__ c1, int* __restrict__ c2) {
  int i = blockIdx.x * blockDim.x + threadIdx.x;
  if (i < NE) {
    atomicAdd(&c1[d1[i]], 1);
    atomicAdd(&c2[d2[i]], 1);
  }
  const int n1 = N_IP * 16;
  const int n2 = N_CONN * 16;
  if (i < n1) {
    int r = i >> 4, g = i & 15;
    u16 v[8];
#pragma unroll
    for (int k = 0; k < 8; k++) v[k] = f2bf(csum[g * 8 + k]);
    *(uint4*)(P1 + (size_t)r * 128 + g * 8) = *(const uint4*)v;
  } else if (i < n1 + n2) {
    int j = i - n1;
    int r = j >> 4, g = j & 15;
    float acc[8] = {0.f, 0.f, 0.f, 0.f, 0.f, 0.f, 0.f, 0.f};
#pragma unroll
    for (int k = 0; k < NF; k++) {
      float f = feat[(size_t)r * NF + k];
      const float* wrow = Wm2 + (size_t)k * 128 + g * 8;
#pragma unroll
      for (int c = 0; c < 8; c++) acc[c] += f * wrow[c];
    }
    u16 v[8];
#pragma unroll
    for (int c = 0; c < 8; c++) v[c] = f2bf(acc[c]);
    *(uint4*)(P2 + (size_t)r * 128 + g * 8) = *(const uint4*)v;
  }
}

// ---------------- merged 3-pass exclusive scan (both segment arrays) ----------------
__global__ void k_scan_part2(const int* __restrict__ cnt1, int* __restrict__ bsum1,
                             int n1, int nb1,
                             const int* __restrict__ cnt2, int* __restrict__ bsum2, int n2) {
  const int* cnt; int* bsum; int n, b;
  if ((int)blockIdx.x < nb1) { cnt = cnt1; bsum = bsum1; n = n1; b = blockIdx.x; }
  else { cnt = cnt2; bsum = bsum2; n = n2; b = blockIdx.x - nb1; }
  int t = threadIdx.x;
  int base = b * 1024 + t * 4;
  int s = 0;
#pragma unroll
  for (int i = 0; i < 4; i++) { int j = base + i; if (j < n) s += cnt[j]; }
  for (int d = 32; d > 0; d >>= 1) s += __shfl_xor(s, d, 64);
  __shared__ int wred[4];
  int lane = t & 63, wv = t >> 6;
  if (lane == 0) wred[wv] = s;
  __syncthreads();
  if (t == 0) bsum[b] = wred[0] + wred[1] + wred[2] + wred[3];
}

__device__ inline void scan_mid_body(int* bsum, int m, int t) {
  int v = (t < m) ? bsum[t] : 0;
  int lane = t & 63, wv = t >> 6;
  int x = v;
  for (int d = 1; d < 64; d <<= 1) { int y = __shfl_up(x, d, 64); if (lane >= d) x += y; }
  __shared__ int wsum[4];
  if (lane == 63) wsum[wv] = x;
  __syncthreads();
  int add = 0;
  for (int i = 0; i < wv; i++) add += wsum[i];
  int ex = add + x - v;
  if (t < m) bsum[t] = ex;
  __syncthreads();
}

__global__ void k_scan_mid2(int* __restrict__ bsum1, int m1, int* __restrict__ bsum2, int m2) {
  int t = threadIdx.x;
  scan_mid_body(bsum1, m1, t);
  scan_mid_body(bsum2, m2, t);
}

// pass 3: write off AND cur
__global__ void k_scan_final2(const int* __restrict__ cnt1, const int* __restrict__ bsum1,
                              int* __restrict__ off1, int* __restrict__ cur1, int n1, int nb1,
                              const int* __restrict__ cnt2, const int* __restrict__ bsum2,
                              int* __restrict__ off2, int* __restrict__ cur2, int n2) {
  const int* cnt; const int* bsum; int* off; int* cur; int n, b;
  if ((int)blockIdx.x < nb1) {
    cnt = cnt1; bsum = bsum1; off = off1; cur = cur1; n = n1; b = blockIdx.x;
  } else {
    cnt = cnt2; bsum = bsum2; off = off2; cur = cur2; n = n2; b = blockIdx.x - nb1;
  }
  int t = threadIdx.x;
  int base = b * 1024 + t * 4;
  int vals[4]; int s = 0;
#pragma unroll
  for (int i = 0; i < 4; i++) {
    int j = base + i;
    vals[i] = (j < n) ? cnt[j] : 0;
    s += vals[i];
  }
  int lane = t & 63, wv = t >> 6;
  int x = s;
  for (int d = 1; d < 64; d <<= 1) { int y = __shfl_up(x, d, 64); if (lane >= d) x += y; }
  __shared__ int wsum[4];
  if (lane == 63) wsum[wv] = x;
  __syncthreads();
  int add = 0;
  for (int i = 0; i < wv; i++) add += wsum[i];
  int run = add + x - s + bsum[b];
#pragma unroll
  for (int i = 0; i < 4; i++) {
    int j = base + i;
    if (j < n) { off[j] = run; cur[j] = run; }
    run += vals[i];
  }
}

__global__ void k_scatter(const int* __restrict__ s1, const int* __restrict__ d1,
                          const int* __restrict__ s2, const int* __restrict__ d2,
                          int* __restrict__ cur1, int* __restrict__ cur2,
                          int* __restrict__ o1, int* __restrict__ o2) {
  int e = blockIdx.x * blockDim.x + threadIdx.x;
  if (e >= NE) return;
  int p1 = atomicAdd(&cur1[d1[e]], 1);
  o1[p1] = s1[e];
  int p2 = atomicAdd(&cur2[d2[e]], 1);
  o2[p2] = s2[e];
}

// ---------------- fused message+GRU+nextP (40960 B LDS, 4 blocks/CU) ----------------
// All LDS staging via global_load_lds (zero staging VGPRs -> no spill); all GEMM B
// operands read from LDS via ds_read_b128 (low latency). Wq/Wp staged in two 64-col
// halves through a 16KB region0 buffer; GRU weights x/h ping-pong (12KB each).
// LDS map: region0 [0,24576): Wls/Qb+Xb [0,16384) | bufA [0,12288) bufB [12288,24576)
//          offLs/cntLs [24064,24576) (dead before GRU) | Hls [24576,40960)
__global__ __launch_bounds__(256, 4) void k_msggru(
    u16* __restrict__ st1, const u16* __restrict__ wq1, const float* __restrict__ qb1,
    const u16* __restrict__ P1g, const int* __restrict__ srcs1g,
    const int* __restrict__ off1g, const int* __restrict__ cnt1g,
    const u16* __restrict__ wx1, const u16* __restrict__ wh1, const float* __restrict__ gb1,
    const u16* __restrict__ wp1, u16* __restrict__ Pn1, int r1, int tiles1,
    u16* __restrict__ st2, const u16* __restrict__ wq2, const float* __restrict__ qb2,
    const u16* __restrict__ P2g, const int* __restrict__ srcs2g,
    const int* __restrict__ off2g, const int* __restrict__ cnt2g,
    const u16* __restrict__ wx2, const u16* __restrict__ wh2, const float* __restrict__ gb2,
    const u16* __restrict__ wp2, u16* __restrict__ Pn2, int r2, int doP) {
  __shared__ __align__(16) char smem[40960];
  u16* Wls = (u16*)smem;                   // 64x128 bf16 swizzled half (16KB), Wq/Wp
  u16* Qb = (u16*)smem;                    // 64x128 bf16 (16KB); Xb overlays swizzled
  u16* bufA = (u16*)smem;                  // GRU x-gates chunk (12KB)
  u16* bufB = (u16*)(smem + 12288);        // GRU h-gates chunk (12KB)
  u16* Hls = (u16*)(smem + 24576);         // 64x128 bf16 swizzled (16KB), whole kernel
  int* offLs = (int*)(smem + 24064);       // 256B, dead before GRU
  int* cntLs = (int*)(smem + 24320);       // 256B
  u16* H; const u16* Wqb; const float* qbias; const u16* P;
  const int* srcs; const int* off; const int* cnt;
  const u16* Wxb; const u16* Whb; const float* gbias;
  const u16* Wpt; u16* Pn; int rows, bm;
  if ((int)blockIdx.x < tiles1) {
    H = st1; Wqb = wq1; qbias = qb1; P = P1g; srcs = srcs1g; off = off1g; cnt = cnt1g;
    Wxb = wx1; Whb = wh1; gbias = gb1; Wpt = wp1; Pn = Pn1; rows = r1; bm = blockIdx.x * 64;
  } else {
    H = st2; Wqb = wq2; qbias = qb2; P = P2g; srcs = srcs2g; off = off2g; cnt = cnt2g;
    Wxb = wx2; Whb = wh2; gbias = gb2; Wpt = wp2; Pn = Pn2; rows = r2;
    bm = (blockIdx.x - tiles1) * 64;
  }
  const int tid = threadIdx.x, wv = tid >> 6, lane = tid & 63;
  const int lrow = lane & 15, quad = lane >> 4;
  const int slot = lane & 15;
  const int rowl = wv * 4 + (lane >> 4);  // 0..15, row/col index of this lane's 16B chunk
  // --- phase A: issue Wq half0 + H staging (linear LDS dest, pre-swizzled global src) ---
#pragma unroll
  for (int i = 0; i < 4; i++)
    gld16(Wqb + (size_t)(i * 16 + rowl) * 128 + ((slot ^ rowl) * 8),
          Wls + (size_t)(i * 16 + wv * 4) * 128 + lane * 8);
#pragma unroll
  for (int i = 0; i < 4; i++)
    gld16(H + (size_t)(bm + i * 16 + rowl) * 128 + ((slot ^ rowl) * 8),
          Hls + (size_t)(i * 16 + wv * 4) * 128 + lane * 8);
  if (tid < 64) {
    int node = bm + tid;
    offLs[tid] = (node < rows) ? off[node] : 0;
    cntLs[tid] = (node < rows) ? cnt[node] : 0;
  }
  __syncthreads();  // Wq h0 + Hls ready
  // state A-frags (serve Q-GEMM and GRU h-GEMM)
  bf16x8 ah[4];
#pragma unroll
  for (int ks = 0; ks < 4; ks++)
    ah[ks] = *(const bf16x8*)(Hls + (size_t)(wv * 16 + lrow) * 128 + (((ks * 4 + quad) ^ lrow) * 8));
  // --- Q-GEMM half0 (cols 0..63) ---
  floatx4 acc[8];
#pragma unroll
  for (int ct = 0; ct < 8; ct++) acc[ct] = {0.f, 0.f, 0.f, 0.f};
#pragma unroll
  for (int ks = 0; ks < 4; ks++) {
#pragma unroll
    for (int j = 0; j < 4; j++) {
      bf16x8 b = *(const bf16x8*)(Wls + (size_t)(j * 16 + lrow) * 128 + (((4 * ks + quad) ^ lrow) * 8));
      acc[j] = __builtin_amdgcn_mfma_f32_16x16x32_bf16(ah[ks], b, acc[j], 0, 0, 0);
    }
  }
  __syncthreads();  // h0 reads done
#pragma unroll
  for (int i = 0; i < 4; i++)  // stage half1 (cols 64..127)
    gld16(Wqb + (size_t)(64 + i * 16 + rowl) * 128 + ((slot ^ rowl) * 8),
          Wls + (size_t)(i * 16 + wv * 4) * 128 + lane * 8);
  __syncthreads();  // h1 ready
#pragma unroll
  for (int ks = 0; ks < 4; ks++) {
#pragma unroll
    for (int j = 0; j < 4; j++) {
      bf16x8 b = *(const bf16x8*)(Wls + (size_t)(j * 16 + lrow) * 128 + (((4 * ks + quad) ^ lrow) * 8));
      acc[4 + j] = __builtin_amdgcn_mfma_f32_16x16x32_bf16(ah[ks], b, acc[4 + j], 0, 0, 0);
    }
  }
  __syncthreads();  // h1 reads done; region0 becomes Qb
  // --- write Q (+bias) as bf16, plain [row][col] ---
#pragma unroll
  for (int ct = 0; ct < 8; ct++) {
    int col = ct * 16 + lrow;
    float bv = qbias[col];
#pragma unroll
    for (int reg = 0; reg < 4; reg++) {
      int lr = wv * 16 + quad * 4 + reg;
      Qb[(size_t)lr * 128 + col] = f2bf(acc[ct][reg] + bv);
    }
  }
  __syncthreads();
  // --- gather-mean: X[node] = mean_e relu(P[src_e] + Q[node]) -> Xb (=Qb, swizzled slots)
#pragma unroll
  for (int it = 0; it < 4; it++) {
    int task = it * 256 + tid;
    int nl = task >> 4, g = task & 15;
    int node = bm + nl;
    if (node >= rows) continue;
    int c8 = g << 3;
    float q[8];
    {
      uint4 qv = *(const uint4*)(Qb + (size_t)nl * 128 + c8);
      unsigned qq[4] = {qv.x, qv.y, qv.z, qv.w};
#pragma unroll
      for (int k = 0; k < 4; k++) {
        q[2 * k] = __uint_as_float(qq[k] << 16);
        q[2 * k + 1] = __uint_as_float(qq[k] & 0xffff0000u);
      }
    }
    float acg[8] = {0.f, 0.f, 0.f, 0.f, 0.f, 0.f, 0.f, 0.f};
    int o = offLs[nl], n = cntLs[nl];
    int i = 0;
    for (; i + 4 <= n; i += 4) {
      int s0 = srcs[o + i], s1 = srcs[o + i + 1], s2 = srcs[o + i + 2], s3 = srcs[o + i + 3];
      uint4 v0 = *(const uint4*)(P + (size_t)s0 * 128 + c8);
      uint4 v1 = *(const uint4*)(P + (size_t)s1 * 128 + c8);
      uint4 v2 = *(const uint4*)(P + (size_t)s2 * 128 + c8);
      uint4 v3 = *(const uint4*)(P + (size_t)s3 * 128 + c8);
      unsigned w[16] = {v0.x, v0.y, v0.z, v0.w, v1.x, v1.y, v1.z, v1.w,
                        v2.x, v2.y, v2.z, v2.w, v3.x, v3.y, v3.z, v3.w};
#pragma unroll
      for (int e = 0; e < 4; e++)
#pragma unroll
        for (int k = 0; k < 4; k++) {
          unsigned ww = w[e * 4 + k];
          float lo = __uint_as_float(ww << 16);
          float hi = __uint_as_float(ww & 0xffff0000u);
          acg[2 * k] += fmaxf(lo + q[2 * k], 0.f);
          acg[2 * k + 1] += fmaxf(hi + q[2 * k + 1], 0.f);
        }
    }
    for (; i < n; i++) {
      int s0 = srcs[o + i];
      uint4 v0 = *(const uint4*)(P + (size_t)s0 * 128 + c8);
      unsigned w[4] = {v0.x, v0.y, v0.z, v0.w};
#pragma unroll
      for (int k = 0; k < 4; k++) {
        unsigned ww = w[k];
        float lo = __uint_as_float(ww << 16);
        float hi = __uint_as_float(ww & 0xffff0000u);
        acg[2 * k] += fmaxf(lo + q[2 * k], 0.f);
        acg[2 * k + 1] += fmaxf(hi + q[2 * k + 1], 0.f);
      }
    }
    float inv = 1.f / fmaxf((float)n, 1.f);
    bf16x8 ov;
#pragma unroll
    for (int k = 0; k < 8; k++) ov[k] = (short)f2bf(acg[k] * inv);
    *(bf16x8*)(Qb + (size_t)nl * 128 + ((g ^ (nl & 15)) * 8)) = ov;  // Xb overlay
  }
  __syncthreads();
  // --- x A-frags from Xb (= Qb region, swizzled) ---
  bf16x8 ax[4];
#pragma unroll
  for (int ks = 0; ks < 4; ks++)
    ax[ks] = *(const bf16x8*)(Qb + (size_t)(wv * 16 + lrow) * 128 + (((ks * 4 + quad) ^ lrow) * 8));
  const int lr0 = wv * 16 + quad * 4;
  __syncthreads();  // all Xb/Qb reads done; region0 free for GRU staging
  // --- GRU chunk loop: x/h ping-pong via global_load_lds ---
  // bufX[(j*16+c)*128 + s*8] = W[(j*128 + ch*16 + c)*128 + (s^c)*8]
#pragma unroll
  for (int j = 0; j < 3; j++)  // stage x(0) -> bufA
    gld16(Wxb + (size_t)(j * 128 + 0 * 16 + rowl) * 128 + ((slot ^ rowl) * 8),
          bufA + (size_t)(j * 16 + wv * 4) * 128 + lane * 8);
  for (int ch = 0; ch < 8; ch++) {
    __syncthreads();  // bufA=x(ch) ready; prev bufB reads done
#pragma unroll
    for (int j = 0; j < 3; j++)  // stage h(ch) -> bufB (overlaps MFMA-x)
      gld16(Whb + (size_t)(j * 128 + ch * 16 + rowl) * 128 + ((slot ^ rowl) * 8),
            bufB + (size_t)(j * 16 + wv * 4) * 128 + lane * 8);
    floatx4 gacc[3][2];
#pragma unroll
    for (int g = 0; g < 3; g++) {
      gacc[g][0] = {0.f, 0.f, 0.f, 0.f};
      gacc[g][1] = {0.f, 0.f, 0.f, 0.f};
    }
#pragma unroll
    for (int ks = 0; ks < 4; ks++) {
      int posu = ((4 * ks + quad) ^ lrow) * 8;
#pragma unroll
      for (int g = 0; g < 3; g++) {
        bf16x8 bx = *(const bf16x8*)(bufA + (size_t)(g * 16 + lrow) * 128 + posu);
        gacc[g][0] = __builtin_amdgcn_mfma_f32_16x16x32_bf16(ax[ks], bx, gacc[g][0], 0, 0, 0);
      }
    }
    __syncthreads();  // bufB=h(ch) ready; bufA reads done
    if (ch < 7) {
#pragma unroll
      for (int j = 0; j < 3; j++)  // stage x(ch+1) -> bufA (overlaps MFMA-h + epilogue)
        gld16(Wxb + (size_t)(j * 128 + (ch + 1) * 16 + rowl) * 128 + ((slot ^ rowl) * 8),
              bufA + (size_t)(j * 16 + wv * 4) * 128 + lane * 8);
    }
#pragma unroll
    for (int ks = 0; ks < 4; ks++) {
      int posu = ((4 * ks + quad) ^ lrow) * 8;
#pragma unroll
      for (int g = 0; g < 3; g++) {
        bf16x8 bh = *(const bf16x8*)(bufB + (size_t)(g * 16 + lrow) * 128 + posu);
        gacc[g][1] = __builtin_amdgcn_mfma_f32_16x16x32_bf16(ah[ks], bh, gacc[g][1], 0, 0, 0);
      }
    }
    int hcol = ch * 16 + lrow;
    float bxz = gbias[hcol];
    float bxr = gbias[128 + hcol];
    float bxh = gbias[256 + hcol];
    float bhz = gbias[384 + hcol];
    float bhr = gbias[384 + 128 + hcol];
    float bhh = gbias[384 + 256 + hcol];
    int ggr = 2 * ch + (lrow >> 3);
    int gel = lrow & 7;
#pragma unroll
    for (int reg = 0; reg < 4; reg++) {
      int lr = lr0 + reg;
      float xz = gacc[0][0][reg] + bxz;
      float xr = gacc[1][0][reg] + bxr;
      float xh = gacc[2][0][reg] + bxh;
      float hz = gacc[0][1][reg] + bhz;
      float hr = gacc[1][1][reg] + bhr;
      float hh = gacc[2][1][reg] + bhh;
      float z = fsigmoid(xz + hz);
      float rr = fsigmoid(xr + hr);
      float hc = ftanh(xh + rr * hh);
      u16* hp = Hls + (size_t)lr * 128 + ((ggr ^ (lr & 15)) * 8) + gel;
      float hold = bf2f(*hp);
      *hp = f2bf(z * hold + (1.f - z) * hc);
    }
  }
  __syncthreads();  // Hls updated block-wide; bufA/bufB reads done
  // --- coalesced state write-out ---
#pragma unroll
  for (int i = 0; i < 4; i++) {
    int task = i * 256 + tid;
    int row = task >> 4, g = task & 15;
    int grow = bm + row;
    if (grow < rows)
      *(uint4*)(H + (size_t)grow * 128 + g * 8) =
          *(const uint4*)(Hls + (size_t)row * 128 + ((g ^ (row & 15)) * 8));
  }
  if (!doP) return;
  // --- fused next-round P: Pn = h_new @ Wm_top, Wp staged in two halves ---
  bf16x8 ah2[4];
#pragma unroll
  for (int ks = 0; ks < 4; ks++)
    ah2[ks] = *(const bf16x8*)(Hls + (size_t)(wv * 16 + lrow) * 128 + (((ks * 4 + quad) ^ lrow) * 8));
#pragma unroll
  for (int i = 0; i < 4; i++)  // stage Wp half0 into region0 (free after GRU)
    gld16(Wpt + (size_t)(i * 16 + rowl) * 128 + ((slot ^ rowl) * 8),
          Wls + (size_t)(i * 16 + wv * 4) * 128 + lane * 8);
  __syncthreads();  // Wp h0 ready; all Hls reads (writeout + ah2) done block-wide
#pragma unroll
  for (int ct = 0; ct < 8; ct++) acc[ct] = {0.f, 0.f, 0.f, 0.f};
#pragma unroll
  for (int ks = 0; ks < 4; ks++) {
#pragma unroll
    for (int j = 0; j < 4; j++) {
      bf16x8 b = *(const bf16x8*)(Wls + (size_t)(j * 16 + lrow) * 128 + (((4 * ks + quad) ^ lrow) * 8));
      acc[j] = __builtin_amdgcn_mfma_f32_16x16x32_bf16(ah2[ks], b, acc[j], 0, 0, 0);
    }
  }
  __syncthreads();  // h0 reads done
#pragma unroll
  for (int i = 0; i < 4; i++)  // stage Wp half1
    gld16(Wpt + (size_t)(64 + i * 16 + rowl) * 128 + ((slot ^ rowl) * 8),
          Wls + (size_t)(i * 16 + wv * 4) * 128 + lane * 8);
  __syncthreads();  // h1 ready
#pragma unroll
  for (int ks = 0; ks < 4; ks++) {
#pragma unroll
    for (int j = 0; j < 4; j++) {
      bf16x8 b = *(const bf16x8*)(Wls + (size_t)(j * 16 + lrow) * 128 + (((4 * ks + quad) ^ lrow) * 8));
      acc[4 + j] = __builtin_amdgcn_mfma_f32_16x16x32_bf16(ah2[ks], b, acc[4 + j], 0, 0, 0);
    }
  }
  // Cls bounce over dead Hls (all Hls reads drained two barriers ago; no overlap w/ Wls)
  u16* Cls = Hls;
#pragma unroll
  for (int ct = 0; ct < 8; ct++) {
    int col = ct * 16 + lrow;
#pragma unroll
    for (int reg = 0; reg < 4; reg++) {
      int lr = wv * 16 + quad * 4 + reg;
      Cls[(size_t)lr * 128 + col] = f2bf(acc[ct][reg]);
    }
  }
  __syncthreads();
#pragma unroll
  for (int i = 0; i < 4; i++) {
    int task = i * 256 + tid;
    int row = task >> 4, g = task & 15;
    int grow = bm + row;
    if (grow < rows)
      *(uint4*)(Pn + (size_t)grow * 128 + g * 8) =
          *(const uint4*)(Cls + (size_t)row * 128 + g * 8);
  }
}

// ---------------- fully fused readout: 2 LDS-staged GEMMs + parallel logits+softmax ----------------
__global__ __launch_bounds__(256, 4) void k_readout2(
    const u16* __restrict__ S, const u16* __restrict__ W1b, const float* __restrict__ b1,
    const u16* __restrict__ W2b, const float* __restrict__ b2,
    const float* __restrict__ W3, const float* __restrict__ b3,
    float* __restrict__ out, int M) {
  __shared__ __align__(16) char smem[33792];
  u16* Wls = (u16*)smem;                        // W1 swizzled 32KB [0,32768)
  u16* H1ls = (u16*)smem;                       // 64x136 bf16 [0,17408)
  u16* W2ls = (u16*)(smem + 17408);             // W2 swizzled 16KB [17408,33792)
  u16* H2ls = (u16*)smem;                       // 64x72 bf16 [0,9216)
  float* W3ls = (float*)(smem + 9216);          // 960 f32
  float* b3ls = (float*)(smem + 9216 + 3840);
  const int tid = threadIdx.x, wv = tid >> 6, lane = tid & 63;
  const int lrow = lane & 15, quad = lane >> 4;
  const int slot = lane & 15;
  const int rowl = wv * 4 + (lane >> 4);
  const int bm = blockIdx.x * 64;
  // stage W1 full 128 cols (swizzled) via global_load_lds
#pragma unroll
  for (int i = 0; i < 8; i++)
    gld16(W1b + (size_t)(i * 16 + rowl) * 128 + ((slot ^ rowl) * 8),
          Wls + (size_t)(i * 16 + wv * 4) * 128 + lane * 8);
  const int arow = bm + wv * 16 + lrow;
  const bool arv = arow < M;
  const bf16x8 zv = {0, 0, 0, 0, 0, 0, 0, 0};
  bf16x8 a[4];
#pragma unroll
  for (int ks = 0; ks < 4; ks++)
    a[ks] = arv ? *(const bf16x8*)(S + (size_t)arow * 128 + quad * 8 + ks * 32) : zv;
  __syncthreads();  // W1 ready
  floatx4 acc1[8];
#pragma unroll
  for (int ct = 0; ct < 8; ct++) acc1[ct] = {0.f, 0.f, 0.f, 0.f};
#pragma unroll
  for (int ks = 0; ks < 4; ks++) {
#pragma unroll
    for (int ct = 0; ct < 8; ct++) {
      bf16x8 b = *(const bf16x8*)(Wls + (size_t)(ct * 16 + lrow) * 128 + (((4 * ks + quad) ^ lrow) * 8));
      acc1[ct] = __builtin_amdgcn_mfma_f32_16x16x32_bf16(a[ks], b, acc1[ct], 0, 0, 0);
    }
  }
  __syncthreads();  // W1 reads done; region becomes H1 (+W2 upper)
#pragma unroll
  for (int ct = 0; ct < 8; ct++) {
    int col = ct * 16 + lrow;
    float bv = b1[col];
#pragma unroll
    for (int reg = 0; reg < 4; reg++) {
      int lr = wv * 16 + quad * 4 + reg;
      H1ls[(size_t)lr * 136 + col] = f2bf(fmaxf(acc1[ct][reg] + bv, 0.f));
    }
  }
#pragma unroll
  for (int i = 0; i < 4; i++)  // stage W2 (64 cols, swizzled) alongside H1 writes
    gld16(W2b + (size_t)(i * 16 + rowl) * 128 + ((slot ^ rowl) * 8),
          W2ls + (size_t)(i * 16 + wv * 4) * 128 + lane * 8);
  __syncthreads();  // H1 visible + W2 ready
  bf16x8 a2[4];
#pragma unroll
  for (int ks = 0; ks < 4; ks++)
    a2[ks] = *(const bf16x8*)(H1ls + (size_t)(wv * 16 + lrow) * 136 + quad * 8 + ks * 32);
  floatx4 acc2[4];
#pragma unroll
  for (int ct = 0; ct < 4; ct++) acc2[ct] = {0.f, 0.f, 0.f, 0.f};
#pragma unroll
  for (int ks = 0; ks < 4; ks++) {
#pragma unroll
    for (int ct = 0; ct < 4; ct++) {
      bf16x8 b = *(const bf16x8*)(W2ls + (size_t)(ct * 16 + lrow) * 128 + (((4 * ks + quad) ^ lrow) * 8));
      acc2[ct] = __builtin_amdgcn_mfma_f32_16x16x32_bf16(a2[ks], b, acc2[ct], 0, 0, 0);
    }
  }
  __syncthreads();  // H1 reads done; region becomes H2/W3
#pragma unroll
  for (int ct = 0; ct < 4; ct++) {
    int col = ct * 16 + lrow;
    float bv = b2[col];
#pragma unroll
    for (int reg = 0; reg < 4; reg++) {
      int lr = wv * 16 + quad * 4 + reg;
      H2ls[(size_t)lr * 72 + col] = f2bf(fmaxf(acc2[ct][reg] + bv, 0.f));
    }
  }
  for (int l = tid; l < 960; l += 256) W3ls[l] = W3[l];
  if (tid < 15) b3ls[tid] = b3[tid];
  __syncthreads();
  // --- parallel logits: thread = (row-group, col); 16-lane shuffle softmax ---
  {
    int col = tid & 15;         // 0..14 valid, 15 idle
    int rb = (tid >> 4) * 4;    // 4 rows per thread
    float lg[4] = {0.f, 0.f, 0.f, 0.f};
    if (col < 15) {
      float b3v = b3ls[col];
      lg[0] = b3v; lg[1] = b3v; lg[2] = b3v; lg[3] = b3v;
      for (int k = 0; k < 64; k++) {
        float w = W3ls[k * 15 + col];
#pragma unroll
        for (int r = 0; r < 4; r++)
          lg[r] += bf2f(H2ls[(size_t)(rb + r) * 72 + k]) * w;
      }
    }
#pragma unroll
    for (int r = 0; r < 4; r++) {
      float v = (col < 15) ? lg[r] : -3.0e38f;
      float m = v;
#pragma unroll
      for (int d = 1; d < 16; d <<= 1) m = fmaxf(m, __shfl_xor(m, d, 16));
      float e = (col < 15) ? __expf(lg[r] - m) : 0.f;
      float s = e;
#pragma unroll
      for (int d = 1; d < 16; d <<= 1) s += __shfl_xor(s, d, 16);
      int gr2 = bm + rb + r;
      if (col < 15 && gr2 < M) out[(size_t)gr2 * 15 + col] = e / s;
    }
  }
}

// ---------------- launch ----------------
extern "C" void kernel_launch(void* const* d_in, const int* in_sizes, int n_in,
                              void* d_out, int out_size, void* d_ws, size_t ws_size,
                              hipStream_t stream) {
  const float* feat = (const float*)d_in[0];
  const int* src1 = (const int*)d_in[1];
  const int* dst1 = (const int*)d_in[2];
  const int* src2 = (const int*)d_in[3];
  const int* dst2 = (const int*)d_in[4];
  const float* Wm1 = (const float*)d_in[5];
  const float* bm1 = (const float*)d_in[6];
  const float* Wm2 = (const float*)d_in[7];
  const float* bm2 = (const float*)d_in[8];
  const float* gik = (const float*)d_in[9];
  const float* gir = (const float*)d_in[10];
  const float* gib = (const float*)d_in[11];
  const float* gck = (const float*)d_in[12];
  const float* gcr = (const float*)d_in[13];
  const float* gcb = (const float*)d_in[14];
  const float* Wr1 = (const float*)d_in[15];
  const float* br1 = (const float*)d_in[16];
  const float* Wr2 = (const float*)d_in[17];
  const float* br2 = (const float*)d_in[18];
  const float* Wr3 = (const float*)d_in[19];
  const float* br3 = (const float*)d_in[20];
  float* out = (float*)d_out;

  // ---- workspace layout (u16 units) ----
  u16* w16 = (u16*)d_ws;
  size_t o = 0;
  u16* ip_state = w16 + o;   o += (size_t)N_IP * D;
  u16* conn_state = w16 + o; o += (size_t)N_CONN * D;
  u16* P1a = w16 + o;        o += (size_t)N_IP * D;
  u16* P2a = w16 + o;        o += (size_t)N_CONN * D;
  u16* P1b = w16 + o;        o += (size_t)N_IP * D;
  u16* P2b = w16 + o;        o += (size_t)N_CONN * D;
  u16* gikb = w16 + o;       o += 49152;
  u16* girb = w16 + o;       o += 49152;
  u16* gckb = w16 + o;       o += 49152;
  u16* gcrb = w16 + o;       o += 49152;
  u16* wm1b = w16 + o;       o += 16384;
  u16* wm2b = w16 + o;       o += 16384;
  u16* wm1t = w16 + o;       o += 16384;
  u16* wm2t = w16 + o;       o += 16384;
  u16* wr1b = w16 + o;       o += 16384;
  u16* wr2b = w16 + o;       o += 8192;
  float* csum = (float*)(w16 + o); o += 256;
  int* ip = (int*)(w16 + o);
  int* cnt1 = ip;  ip += N_CONN;
  int* cnt2 = ip;  ip += N_IP;
  int* off1 = ip;  ip += N_CONN;
  int* off2 = ip;  ip += N_IP;
  int* cur1 = ip;  ip += N_CONN;
  int* cur2 = ip;  ip += N_IP;
  int* srcs1 = ip; ip += NE;
  int* srcs2 = ip; ip += NE;
  int* bsum1 = ip; ip += 256;
  int* bsum2 = ip; ip += 256;

  const int BT = 256;

  // ---- fused init + weight prep (+colsum) + analytic round-0 P (+count) ----
  const int nstate = (N_IP + N_CONN) * D;
  k_init_all<<<(nstate + BT - 1) / BT, BT, 0, stream>>>(ip_state, conn_state, feat, cnt1);
  k_prep_all<<<(286848 + BT - 1) / BT, BT, 0, stream>>>(
      gik, gir, gck, gcr, Wm1, Wm2, Wr1, Wr2,
      gikb, girb, gckb, gcrb, wm1b, wm2b, wm1t, wm2t, wr1b, wr2b, csum);
  const int nPinit = (N_IP + N_CONN) * 16;
  k_initP_count<<<(nPinit + BT - 1) / BT, BT, 0, stream>>>(
      csum, feat, Wm2, P1a, P2a, dst1, dst2, cnt1, cnt2);

  // ---- build CSR ----
  const int nb1 = (N_CONN + 1023) / 1024, nb2 = (N_IP + 1023) / 1024;
  k_scan_part2<<<nb1 + nb2, 256, 0, stream>>>(cnt1, bsum1, N_CONN, nb1, cnt2, bsum2, N_IP);
  k_scan_mid2<<<1, 256, 0, stream>>>(bsum1, nb1, bsum2, nb2);
  k_scan_final2<<<nb1 + nb2, 256, 0, stream>>>(cnt1, bsum1, off1, cur1, N_CONN, nb1,
                                               cnt2, bsum2, off2, cur2, N_IP);
  k_scatter<<<(NE + BT - 1) / BT, BT, 0, stream>>>(src1, dst1, src2, dst2,
                                                   cur1, cur2, srcs1, srcs2);

  const int t64ip = (N_IP + 63) / 64;       // 313
  const int t64cn = (N_CONN + 63) / 64;     // 1563

  u16* P1buf[2] = {P1a, P1b};
  u16* P2buf[2] = {P2a, P2b};
  for (int t = 0; t < T_ROUNDS; t++) {
    int cu = t & 1, nx = cu ^ 1;
    // ip side FIRST (heaviest gather blocks -> better makespan), conn side second.
    // Each side also emits next round's P from the freshly updated state (ping-pong).
    k_msggru<<<t64ip + t64cn, 256, 0, stream>>>(
        ip_state, wm2b, bm2, P2buf[cu], srcs2, off2, cnt2, gikb, girb, gib,
        wm1t, P1buf[nx], N_IP, t64ip,
        conn_state, wm1b, bm1, P1buf[cu], srcs1, off1, cnt1, gckb, gcrb, gcb,
        wm2t, P2buf[nx], N_CONN, (t < T_ROUNDS - 1) ? 1 : 0);
  }

  k_readout2<<<t64cn, 256, 0, stream>>>(conn_state, wr1b, br1, wr2b, br2,
                                        Wr3, br3, out, N_CONN);
}